// Round 19
// baseline (64.623 us; speedup 1.0000x reference)
//
#include <hip/hip_runtime.h>

#define SENT    256
#define BATCH   64
#define WLEN    16
#define D_WORDE 300
#define D_CHARE 50
#define OUT_CH  200
#define KSIZE   3
#define NPOS    14
#define D_OUT   500
#define NWORDS  (SENT * BATCH)

// GEMM geometry: M=16 positions/word, N=13x16=208, K=3*64=192 (kg=kk*64+c)
// Bias folded into K: charP col63 = 1.0, WO[o][191] = conv_b[o]  (max(y+b)=max(y)+b)
#define KPAD      192
#define MPAD      208
#define CHARP_U16 (129 * 64)
#define WO_U16    (MPAD * KPAD)
#define WS_NEED   ((size_t)(CHARP_U16 + WO_U16) * 2)

#define WPB         16                 // words per conv block, single 32KB buffer
#define TILE_TOT    (WPB * 1024 + 128) // + slack rows for last word's taps
#define CONV_BLOCKS (NWORDS / WPB)     // 1024
#define EMB_BLOCKS  (NWORDS / 4)       // 4096
#define GRID        (CONV_BLOCKS + EMB_BLOCKS)   // 5120; conv when blockIdx%5==0

typedef short  short8  __attribute__((ext_vector_type(8)));
typedef ushort ushort8 __attribute__((ext_vector_type(8)));
typedef float  float4v __attribute__((ext_vector_type(4)));

// direct global->LDS (16B/lane, dest = wave-uniform base + lane*16; src per-lane)
#define GLOAD16(SRC, DST)                                                     \
    __builtin_amdgcn_global_load_lds(                                         \
        (const __attribute__((address_space(1))) void*)(SRC),                 \
        (__attribute__((address_space(3))) void*)(DST), 16, 0, 0)

__device__ __forceinline__ ushort f2bf(float f) {
    unsigned u = __float_as_uint(f);
    u = (u + 0x7FFFu + ((u >> 16) & 1u)) >> 16;   // RNE
    return (ushort)u;
}

// ---------- prep: bf16 char table (col63=1.0) + K-major weights (kg191=bias) ----------
__global__ void prep_kernel(const float* __restrict__ W_char,
                            const float* __restrict__ conv_w,
                            const float* __restrict__ conv_b,
                            ushort* __restrict__ ws) {
    int j = blockIdx.x * 256 + threadIdx.x;
    if (j < CHARP_U16) {
        int r = j >> 6, c = j & 63;
        ushort v = 0;
        if (r < 128) {
            if (c < D_CHARE)      v = f2bf(W_char[r * D_CHARE + c]);
            else if (c == 63)     v = 0x3F80;        // 1.0 bf16 (bias lane)
        }
        ws[j] = v;
    }
    int j2 = j - CHARP_U16;
    if (j2 >= 0 && j2 < WO_U16) {
        int o = j2 / KPAD, kg = j2 - o * KPAD;
        int kk = kg >> 6, c = kg & 63;
        float v = 0.f;
        if (o < OUT_CH) {
            if (c < D_CHARE)      v = conv_w[o * (D_CHARE * KSIZE) + c * KSIZE + kk];
            else if (kg == 191)   v = conv_b[o];     // bias rides K-slot 191
        }
        ws[CHARP_U16 + j2] = f2bf(v);
    }
}

__device__ __forceinline__ float redmax14(float4v d, int lg) {
    float m01 = fmaxf(d[0], d[1]);
    float m23 = fmaxf(d[2], d[3]);
    float m = (lg == 3) ? m01 : fmaxf(m01, m23);   // rows 14,15 excluded (garbage-safe)
    m = fmaxf(m, __shfl_xor(m, 16, 64));
    m = fmaxf(m, __shfl_xor(m, 32, 64));
    return m;
}

// NT tiles starting at TBASE, 8 words of half `pair`; B held in regs for all 8 words.
template <int TBASE, int NT>
__device__ __forceinline__ void conv_half(int pair, int lane, int l15, int lg,
                                          const ushort* __restrict__ tile,
                                          const int* offA,
                                          const ushort* __restrict__ WO,
                                          float* __restrict__ out, int block0) {
    short8 B[NT][6];
    #pragma unroll
    for (int i = 0; i < NT; i++) {
        int col = (TBASE + i) * 16 + l15;
        #pragma unroll
        for (int s = 0; s < 6; s++)
            B[i][s] = *(const short8*)&WO[col * KPAD + s * 32 + lg * 8];
    }

    #pragma unroll 1
    for (int r = 0; r < 8; r++) {
        const int widx = pair * 8 + r;
        const int base = widx << 10;
        short8 a[6];
        #pragma unroll
        for (int s = 0; s < 6; s++)
            a[s] = *(const short8*)&tile[base + offA[s]];
        float4v acc[NT];
        #pragma unroll
        for (int i = 0; i < NT; i++) acc[i] = (float4v){0, 0, 0, 0};
        #pragma unroll
        for (int s = 0; s < 6; s++)
            #pragma unroll
            for (int i = 0; i < NT; i++)
                acc[i] = __builtin_amdgcn_mfma_f32_16x16x32_bf16(a[s], B[i][s], acc[i], 0, 0, 0);

        float* obase = out + (size_t)(block0 + widx) * D_OUT + D_WORDE;
        #pragma unroll
        for (int i = 0; i < NT; i++) {
            float mx = redmax14(acc[i], lg);
            int col = (TBASE + i) * 16 + lane;
            if (lane < 16 && col < OUT_CH) obase[col] = mx;   // tile 12: lanes 0..7 only
        }
    }
}

// ---------- fused grid: conv (%5==0, M=2 read-multiplicity) + emb copy blocks ----------
// NO __launch_bounds__ min-waves. VGPR ~245/wave -> 2 waves/SIMD BY DESIGN:
// trades occupancy for halved LDS-read traffic (the measured r18 binder).
__global__ void __launch_bounds__(256)
fused_kernel(const int* __restrict__ words, const int* __restrict__ chars,
             const float* __restrict__ W_word, const ushort* __restrict__ ws,
             float* __restrict__ out) {
    __shared__ __align__(16) ushort tile[TILE_TOT];   // ~33 KB single buffer

    const int tid  = threadIdx.x;
    const int lane = tid & 63;
    const int wave = tid >> 6;

    if (blockIdx.x % 5 != 0) {
        // ---- word embedding: one wave per output row, float4 copy (proven)
        const int eb = blockIdx.x - blockIdx.x / 5 - 1;       // 0..4095
        const int m  = eb * 4 + wave;
        const int idx = words[m];
        const float4v* __restrict__ src = (const float4v*)(W_word + (size_t)idx * D_WORDE);
        float4v* __restrict__ dst = (float4v*)(out + (size_t)m * D_OUT);
        dst[lane] = src[lane];                                 // 75 float4 per row
        if (lane < 75 - 64) dst[64 + lane] = src[64 + lane];
        return;
    }

    const ushort* __restrict__ charP = ws;
    const ushort* __restrict__ WO    = ws + CHARP_U16;
    const int block0 = (blockIdx.x / 5) * WPB;
    const int l15 = lane & 15;
    const int lg  = lane >> 4;
    const int srcblk = (lane & 7) ^ ((lane >> 3) & 7);   // pre-swizzled source block

    // ---- stage: wave stages words {4w .. 4w+3} (2 gloads each), single buffer
    #pragma unroll
    for (int ww = 0; ww < 4; ww++) {
        const int wl = wave * 4 + ww;
        const int m  = block0 + wl;
        const int* __restrict__ cbase = chars + ((m & 63) * SENT + (m >> 6)) * WLEN;
        #pragma unroll
        for (int s = 0; s < 2; s++) {
            const int idv = cbase[s * 8 + (lane >> 3)];
            GLOAD16(charP + idv * 64 + (srcblk << 3), &tile[wl * 1024 + s * 512]);
        }
    }
    __syncthreads();                     // single barrier: drains gloads, all waves free after

    // ---- loop-invariant swizzled LDS read offsets; word stride 1024 u16
    int offA[6];
    #pragma unroll
    for (int s = 0; s < 6; s++) {
        int l  = l15 + (s >> 1);
        int bb = (((s & 1) * 4 + lg) ^ (l & 7));
        offA[s] = l * 64 + (bb << 3);
    }

    // ---- M=2: pair (w>>1) owns 8 words; role (w&1) owns tiles 0-5 or 6-12
    const int pair = wave >> 1;
    if ((wave & 1) == 0)
        conv_half<0, 6>(pair, lane, l15, lg, tile, offA, WO, out, block0);
    else
        conv_half<6, 7>(pair, lane, l15, lg, tile, offA, WO, out, block0);
}

// ---------- fallbacks (tiny ws): round-1 proven kernels ----------
__global__ void __launch_bounds__(256)
word_emb_kernel(const int* __restrict__ words, const float* __restrict__ W_word,
                float* __restrict__ out) {
    int wave = threadIdx.x >> 6, lane = threadIdx.x & 63;
    int m = blockIdx.x * 4 + wave;
    int idx = words[m];
    const float* __restrict__ src = W_word + (size_t)idx * D_WORDE;
    float* __restrict__ dst = out + (size_t)m * D_OUT;
    for (int j = lane; j < D_WORDE; j += 64) dst[j] = src[j];
}

__global__ void __launch_bounds__(256)
char_conv_f32_kernel(const int* __restrict__ chars, const float* __restrict__ W_char,
                     const float* __restrict__ conv_w, const float* __restrict__ conv_b,
                     float* __restrict__ out) {
    __shared__ __align__(16) float xs[D_CHARE * WLEN];
    __shared__ int ids[WLEN];
    int m = blockIdx.x, s = m >> 6, b = m & 63, tid = threadIdx.x;
    if (tid < WLEN) ids[tid] = chars[(b * SENT + s) * WLEN + tid];
    __syncthreads();
    for (int e = tid; e < D_CHARE * WLEN; e += 256) {
        int c = e >> 4, l = e & 15;
        xs[e] = W_char[ids[l] * D_CHARE + c];
    }
    __syncthreads();
    if (tid < OUT_CH) {
        float acc[NPOS];
        #pragma unroll
        for (int p = 0; p < NPOS; p++) acc[p] = 0.f;
        const float4* xs4 = (const float4*)xs;
        for (int c = 0; c < D_CHARE; c++) {
            float4 a0 = xs4[c*4+0], a1 = xs4[c*4+1], a2 = xs4[c*4+2], a3 = xs4[c*4+3];
            float xr[WLEN] = {a0.x,a0.y,a0.z,a0.w, a1.x,a1.y,a1.z,a1.w,
                              a2.x,a2.y,a2.z,a2.w, a3.x,a3.y,a3.z,a3.w};
            #pragma unroll
            for (int k = 0; k < KSIZE; k++) {
                float wv = conv_w[tid * (D_CHARE * KSIZE) + c * KSIZE + k];
                #pragma unroll
                for (int p = 0; p < NPOS; p++) acc[p] = fmaf(wv, xr[p + k], acc[p]);
            }
        }
        float mx = acc[0];
        #pragma unroll
        for (int p = 1; p < NPOS; p++) mx = fmaxf(mx, acc[p]);
        out[(size_t)m * D_OUT + D_WORDE + tid] = mx + conv_b[tid];
    }
}

extern "C" void kernel_launch(void* const* d_in, const int* in_sizes, int n_in,
                              void* d_out, int out_size, void* d_ws, size_t ws_size,
                              hipStream_t stream) {
    const int*   words  = (const int*)d_in[0];
    const int*   chars  = (const int*)d_in[1];
    const float* W_word = (const float*)d_in[2];
    const float* W_char = (const float*)d_in[3];
    const float* conv_w = (const float*)d_in[4];
    const float* conv_b = (const float*)d_in[5];
    float* out = (float*)d_out;

    if (ws_size >= WS_NEED) {
        ushort* ws = (ushort*)d_ws;
        hipLaunchKernelGGL(prep_kernel,
                           dim3((CHARP_U16 + WO_U16 + 255) / 256), dim3(256), 0, stream,
                           W_char, conv_w, conv_b, ws);
        hipLaunchKernelGGL(fused_kernel, dim3(GRID), dim3(256), 0, stream,
                           words, chars, W_word, ws, out);
    } else {
        hipLaunchKernelGGL(word_emb_kernel, dim3(NWORDS / 4), dim3(256), 0, stream,
                           words, W_word, out);
        hipLaunchKernelGGL(char_conv_f32_kernel, dim3(NWORDS), dim3(256), 0, stream,
                           chars, W_char, conv_w, conv_b, out);
    }
}

// Round 20
// 46.920 us; speedup vs baseline: 1.3773x; 1.3773x over previous
//
#include <hip/hip_runtime.h>

#define SENT    256
#define BATCH   64
#define WLEN    16
#define D_WORDE 300
#define D_CHARE 50
#define OUT_CH  200
#define KSIZE   3
#define NPOS    14
#define D_OUT   500
#define NWORDS  (SENT * BATCH)

// GEMM geometry: M=16 positions/word, N=13x16=208, K=3*64=192 (kg=kk*64+c)
// Bias folded into K: charP col63 = 1.0, WO[o][191] = conv_b[o]  (max(y+b)=max(y)+b)
#define KPAD      192
#define MPAD      208
#define CHARP_U16 (129 * 64)
#define WO_U16    (MPAD * KPAD)
#define WS_NEED   ((size_t)(CHARP_U16 + WO_U16) * 2)

#define WPB         32                 // words per conv block (2 halves of 16)
#define HALF_WORDS  16
#define TILE_TOT    (WPB * 1024 + 128) // + 2 slack rows for last word's taps (~66KB)
#define CONV_BLOCKS (NWORDS / WPB)     // 512 blocks x 512 threads = 2 blocks/CU

typedef short  short8  __attribute__((ext_vector_type(8)));
typedef ushort ushort8 __attribute__((ext_vector_type(8)));
typedef float  float4v __attribute__((ext_vector_type(4)));

// direct global->LDS (16B/lane, dest = wave-uniform base + lane*16; src per-lane)
#define GLOAD16(SRC, DST)                                                     \
    __builtin_amdgcn_global_load_lds(                                         \
        (const __attribute__((address_space(1))) void*)(SRC),                 \
        (__attribute__((address_space(3))) void*)(DST), 16, 0, 0)

__device__ __forceinline__ ushort f2bf(float f) {
    unsigned u = __float_as_uint(f);
    u = (u + 0x7FFFu + ((u >> 16) & 1u)) >> 16;   // RNE
    return (ushort)u;
}

// ---------- prep: bf16 char table (col63=1.0) + K-major weights (kg191=bias) ----------
__global__ void prep_kernel(const float* __restrict__ W_char,
                            const float* __restrict__ conv_w,
                            const float* __restrict__ conv_b,
                            ushort* __restrict__ ws) {
    int j = blockIdx.x * 256 + threadIdx.x;
    if (j < CHARP_U16) {
        int r = j >> 6, c = j & 63;
        ushort v = 0;
        if (r < 128) {
            if (c < D_CHARE)      v = f2bf(W_char[r * D_CHARE + c]);
            else if (c == 63)     v = 0x3F80;        // 1.0 bf16 (bias lane)
        }
        ws[j] = v;
    }
    int j2 = j - CHARP_U16;
    if (j2 >= 0 && j2 < WO_U16) {
        int o = j2 / KPAD, kg = j2 - o * KPAD;
        int kk = kg >> 6, c = kg & 63;
        float v = 0.f;
        if (o < OUT_CH) {
            if (c < D_CHARE)      v = conv_w[o * (D_CHARE * KSIZE) + c * KSIZE + kk];
            else if (kg == 191)   v = conv_b[o];     // bias rides K-slot 191
        }
        ws[CHARP_U16 + j2] = f2bf(v);
    }
}

__device__ __forceinline__ float redmax14(float4v d, int lg) {
    float m01 = fmaxf(d[0], d[1]);
    float m23 = fmaxf(d[2], d[3]);
    float m = (lg == 3) ? m01 : fmaxf(m01, m23);   // rows 14,15 excluded (garbage-safe)
    m = fmaxf(m, __shfl_xor(m, 16, 64));
    m = fmaxf(m, __shfl_xor(m, 32, 64));
    return m;
}

// ---------- uniform 512-thread block: 2-phase conv (2-deep A pipe) + emb late ----------
// Pure 2x scale of the r18 champion: same per-wave instruction stream, half the
// per-word share of barriers and B-prologue. 8 waves = (tile-set w&3, sub-half w>>2).
// NO __launch_bounds__ min-waves (r5/r6/r8: force-occupancy => spill/wave cliff).
__global__ void __launch_bounds__(512)
fused_kernel(const int* __restrict__ words, const int* __restrict__ chars,
             const float* __restrict__ W_word, const ushort* __restrict__ ws,
             float* __restrict__ out) {
    __shared__ __align__(16) ushort tile[TILE_TOT];   // ~66 KB -> 2 blocks/CU (LDS-bound)

    const int tid  = threadIdx.x;
    const int lane = tid & 63;
    const int wave = tid >> 6;          // 0..7
    const int wgrp = wave & 3;          // N-tile set {wgrp, wgrp+4, wgrp+8}
    const int wsub = wave >> 2;         // word sub-half within each 16-word half

    const ushort* __restrict__ charP = ws;
    const ushort* __restrict__ WO    = ws + CHARP_U16;
    const int block0 = blockIdx.x * WPB;
    const int l15 = lane & 15;
    const int lg  = lane >> 4;
    const int srcblk = (lane & 7) ^ ((lane >> 3) & 7);   // pre-swizzled source block

    // ---- ids prefetch for BOTH halves (wave stages words {wave*2, wave*2+1}/half)
    int ids[2][2][2];
    #pragma unroll
    for (int h = 0; h < 2; h++)
        #pragma unroll
        for (int ww = 0; ww < 2; ww++) {
            const int m = block0 + h * HALF_WORDS + wave * 2 + ww;
            const int* __restrict__ cbase = chars + ((m & 63) * SENT + (m >> 6)) * WLEN;
            #pragma unroll
            for (int s = 0; s < 2; s++)
                ids[h][ww][s] = cbase[s * 8 + (lane >> 3)];
        }

    // ---- B fragments (latency hides under staging); bias inside K
    short8 B[3][6];
    #pragma unroll
    for (int i = 0; i < 3; i++) {
        int col = (wgrp + 4 * i) * 16 + l15;                  // <= 191
        #pragma unroll
        for (int s = 0; s < 6; s++)
            B[i][s] = *(const short8*)&WO[col * KPAD + s * 32 + lg * 8];
    }

#define STAGE_HALF(h)                                                         \
    {                                                                         \
        _Pragma("unroll")                                                     \
        for (int ww = 0; ww < 2; ww++) {                                      \
            const int wl = (h) * HALF_WORDS + wave * 2 + ww;                  \
            _Pragma("unroll")                                                 \
            for (int s = 0; s < 2; s++) {                                     \
                const ushort* src_ = charP + ids[h][ww][s] * 64 + (srcblk << 3); \
                GLOAD16(src_, &tile[wl * 1024 + s * 512]);                    \
            }                                                                 \
        }                                                                     \
    }

    // ---- loop-invariant swizzled LDS read offsets; word stride 1024 u16
    int offA[6];
    #pragma unroll
    for (int s = 0; s < 6; s++) {
        int l  = l15 + (s >> 1);
        int bb = (((s & 1) * 4 + lg) ^ (l & 7));
        offA[s] = l * 64 + (bb << 3);
    }

#define LOAD_A(dst, widx)                                                     \
    {                                                                         \
        const int base_ = (widx) << 10;                                       \
        _Pragma("unroll")                                                     \
        for (int s = 0; s < 6; s++)                                           \
            dst[s] = *(const short8*)&tile[base_ + offA[s]];                  \
    }

#define MFMA_RED_STORE(a_, widx)                                              \
    {                                                                         \
        float4v acc_[3];                                                      \
        _Pragma("unroll")                                                     \
        for (int i = 0; i < 3; i++) acc_[i] = (float4v){0, 0, 0, 0};          \
        _Pragma("unroll")                                                     \
        for (int s = 0; s < 6; s++)                                           \
            _Pragma("unroll")                                                 \
            for (int i = 0; i < 3; i++)                                       \
                acc_[i] = __builtin_amdgcn_mfma_f32_16x16x32_bf16(            \
                    a_[s], B[i][s], acc_[i], 0, 0, 0);                        \
        float* obase_ = out + (size_t)(block0 + (widx)) * D_OUT + D_WORDE;    \
        _Pragma("unroll")                                                     \
        for (int i = 0; i < 3; i++) {                                         \
            float mx_ = redmax14(acc_[i], lg);                                \
            if (lane < 16) obase_[(wgrp + 4 * i) * 16 + lane] = mx_;          \
        }                                                                     \
    }

// 2-deep software-pipelined phase: this wave's 8 words = half h, sub-half wsub
#define PHASE1_HALF_PIPE(h)                                                   \
    {                                                                         \
        const int w0_ = (h) * HALF_WORDS + wsub * 8;                          \
        short8 aA[6], aB[6];                                                  \
        LOAD_A(aA, w0_)                                                       \
        _Pragma("unroll 1")                                                   \
        for (int r = w0_; r < w0_ + 8; r += 2) {                              \
            LOAD_A(aB, r + 1)                                                 \
            MFMA_RED_STORE(aA, r)                                             \
            if (r + 2 < w0_ + 8) LOAD_A(aA, r + 2)                            \
            MFMA_RED_STORE(aB, r + 1)                                         \
        }                                                                     \
    }

    // ---- 2-phase pipeline: stage0 | bar | stage1-issue, compute0 | bar | compute1
    STAGE_HALF(0)
    __syncthreads();                       // drains stage0 (emb not yet issued)
    STAGE_HALF(1)                          // flies under compute of half 0
    PHASE1_HALF_PIPE(0)
    __syncthreads();                       // drains stage1

    // ---- T14 issue-early (AFTER last barrier): 4 word-emb rows -> registers.
    // No barrier follows, so the HBM latency hides under phase1(1)+phase2.
    const int me = block0 + wave * 4;
    const bool tail = lane < (75 - 64);
    float4v e0[4], e1[4];
    #pragma unroll
    for (int r = 0; r < 4; r++) {
        const float4v* __restrict__ src =
            (const float4v*)(W_word + (size_t)words[me + r] * D_WORDE);
        e0[r] = src[lane];
        e1[r] = tail ? src[64 + lane] : (float4v){0, 0, 0, 0};
    }

    PHASE1_HALF_PIPE(1)

    // ---- phase 2: tile 12 (channels 192..199); wave does 4 words (both halves valid)
    {
        short8 B12[6];
        #pragma unroll
        for (int s = 0; s < 6; s++)
            B12[s] = *(const short8*)&WO[(192 + l15) * KPAD + s * 32 + lg * 8];

        #pragma unroll 1
        for (int r2 = 0; r2 < 4; r2++) {
            const int widx = wave * 4 + r2;
            short8 a[6];
            LOAD_A(a, widx)
            float4v acc = {0, 0, 0, 0};
            #pragma unroll
            for (int s = 0; s < 6; s++)
                acc = __builtin_amdgcn_mfma_f32_16x16x32_bf16(a[s], B12[s], acc, 0, 0, 0);
            float mx = redmax14(acc, lg);
            if (lane < 8)
                out[(size_t)(block0 + widx) * D_OUT + D_WORDE + 192 + lane] = mx;
        }
    }

    // ---- T14 write-late: emb rows from registers
    #pragma unroll
    for (int r = 0; r < 4; r++) {
        float4v* __restrict__ dst = (float4v*)(out + (size_t)(me + r) * D_OUT);
        dst[lane] = e0[r];
        if (tail) dst[64 + lane] = e1[r];
    }
#undef STAGE_HALF
#undef LOAD_A
#undef MFMA_RED_STORE
#undef PHASE1_HALF_PIPE
}

// ---------- fallbacks (tiny ws): round-1 proven kernels ----------
__global__ void __launch_bounds__(256)
word_emb_kernel(const int* __restrict__ words, const float* __restrict__ W_word,
                float* __restrict__ out) {
    int wave = threadIdx.x >> 6, lane = threadIdx.x & 63;
    int m = blockIdx.x * 4 + wave;
    int idx = words[m];
    const float* __restrict__ src = W_word + (size_t)idx * D_WORDE;
    float* __restrict__ dst = out + (size_t)m * D_OUT;
    for (int j = lane; j < D_WORDE; j += 64) dst[j] = src[j];
}

__global__ void __launch_bounds__(256)
char_conv_f32_kernel(const int* __restrict__ chars, const float* __restrict__ W_char,
                     const float* __restrict__ conv_w, const float* __restrict__ conv_b,
                     float* __restrict__ out) {
    __shared__ __align__(16) float xs[D_CHARE * WLEN];
    __shared__ int ids[WLEN];
    int m = blockIdx.x, s = m >> 6, b = m & 63, tid = threadIdx.x;
    if (tid < WLEN) ids[tid] = chars[(b * SENT + s) * WLEN + tid];
    __syncthreads();
    for (int e = tid; e < D_CHARE * WLEN; e += 256) {
        int c = e >> 4, l = e & 15;
        xs[e] = W_char[ids[l] * D_CHARE + c];
    }
    __syncthreads();
    if (tid < OUT_CH) {
        float acc[NPOS];
        #pragma unroll
        for (int p = 0; p < NPOS; p++) acc[p] = 0.f;
        const float4* xs4 = (const float4*)xs;
        for (int c = 0; c < D_CHARE; c++) {
            float4 a0 = xs4[c*4+0], a1 = xs4[c*4+1], a2 = xs4[c*4+2], a3 = xs4[c*4+3];
            float xr[WLEN] = {a0.x,a0.y,a0.z,a0.w, a1.x,a1.y,a1.z,a1.w,
                              a2.x,a2.y,a2.z,a2.w, a3.x,a3.y,a3.z,a3.w};
            #pragma unroll
            for (int k = 0; k < KSIZE; k++) {
                float wv = conv_w[tid * (D_CHARE * KSIZE) + c * KSIZE + k];
                #pragma unroll
                for (int p = 0; p < NPOS; p++) acc[p] = fmaf(wv, xr[p + k], acc[p]);
            }
        }
        float mx = acc[0];
        #pragma unroll
        for (int p = 1; p < NPOS; p++) mx = fmaxf(mx, acc[p]);
        out[(size_t)m * D_OUT + D_WORDE + tid] = mx + conv_b[tid];
    }
}

extern "C" void kernel_launch(void* const* d_in, const int* in_sizes, int n_in,
                              void* d_out, int out_size, void* d_ws, size_t ws_size,
                              hipStream_t stream) {
    const int*   words  = (const int*)d_in[0];
    const int*   chars  = (const int*)d_in[1];
    const float* W_word = (const float*)d_in[2];
    const float* W_char = (const float*)d_in[3];
    const float* conv_w = (const float*)d_in[4];
    const float* conv_b = (const float*)d_in[5];
    float* out = (float*)d_out;

    if (ws_size >= WS_NEED) {
        ushort* ws = (ushort*)d_ws;
        hipLaunchKernelGGL(prep_kernel,
                           dim3((CHARP_U16 + WO_U16 + 255) / 256), dim3(256), 0, stream,
                           W_char, conv_w, conv_b, ws);
        hipLaunchKernelGGL(fused_kernel, dim3(CONV_BLOCKS), dim3(512), 0, stream,
                           words, chars, W_word, ws, out);
    } else {
        hipLaunchKernelGGL(word_emb_kernel, dim3(NWORDS / 4), dim3(256), 0, stream,
                           words, W_word, out);
        hipLaunchKernelGGL(char_conv_f32_kernel, dim3(NWORDS), dim3(256), 0, stream,
                           chars, W_char, conv_w, conv_b, out);
    }
}

// Round 21
// 45.794 us; speedup vs baseline: 1.4112x; 1.0246x over previous
//
#include <hip/hip_runtime.h>

#define SENT    256
#define BATCH   64
#define WLEN    16
#define D_WORDE 300
#define D_CHARE 50
#define OUT_CH  200
#define KSIZE   3
#define NPOS    14
#define D_OUT   500
#define NWORDS  (SENT * BATCH)

// GEMM geometry: M=16 positions/word, N=13x16=208, K=3*64=192 (kg=kk*64+c)
// Bias folded into K: charP col63 = 1.0, WO[o][191] = conv_b[o]  (max(y+b)=max(y)+b)
#define KPAD      192
#define MPAD      208
#define CHARP_U16 (129 * 64)
#define WO_U16    (MPAD * KPAD)
#define WS_NEED   ((size_t)(CHARP_U16 + WO_U16) * 2)

#define WPB         16                 // words per conv block (2 halves of 8)
#define HALF_U16    8192               // 8 words * 16 rows * 64 cols
#define TILE_TOT    (2 * HALF_U16 + 128)  // + 2 slack rows for last word's taps
#define CONV_BLOCKS (NWORDS / WPB)     // 1024 uniform blocks (emb folded in)

typedef short  short8  __attribute__((ext_vector_type(8)));
typedef ushort ushort8 __attribute__((ext_vector_type(8)));
typedef float  float4v __attribute__((ext_vector_type(4)));

// direct global->LDS (16B/lane, dest = wave-uniform base + lane*16; src per-lane)
#define GLOAD16(SRC, DST)                                                     \
    __builtin_amdgcn_global_load_lds(                                         \
        (const __attribute__((address_space(1))) void*)(SRC),                 \
        (__attribute__((address_space(3))) void*)(DST), 16, 0, 0)

__device__ __forceinline__ ushort f2bf(float f) {
    unsigned u = __float_as_uint(f);
    u = (u + 0x7FFFu + ((u >> 16) & 1u)) >> 16;   // RNE
    return (ushort)u;
}

// ---------- prep: bf16 char table (col63=1.0) + K-major weights (kg191=bias) ----------
__global__ void prep_kernel(const float* __restrict__ W_char,
                            const float* __restrict__ conv_w,
                            const float* __restrict__ conv_b,
                            ushort* __restrict__ ws) {
    int j = blockIdx.x * 256 + threadIdx.x;
    if (j < CHARP_U16) {
        int r = j >> 6, c = j & 63;
        ushort v = 0;
        if (r < 128) {
            if (c < D_CHARE)      v = f2bf(W_char[r * D_CHARE + c]);
            else if (c == 63)     v = 0x3F80;        // 1.0 bf16 (bias lane)
        }
        ws[j] = v;
    }
    int j2 = j - CHARP_U16;
    if (j2 >= 0 && j2 < WO_U16) {
        int o = j2 / KPAD, kg = j2 - o * KPAD;
        int kk = kg >> 6, c = kg & 63;
        float v = 0.f;
        if (o < OUT_CH) {
            if (c < D_CHARE)      v = conv_w[o * (D_CHARE * KSIZE) + c * KSIZE + kk];
            else if (kg == 191)   v = conv_b[o];     // bias rides K-slot 191
        }
        ws[CHARP_U16 + j2] = f2bf(v);
    }
}

__device__ __forceinline__ float redmax14(float4v d, int lg) {
    float m01 = fmaxf(d[0], d[1]);
    float m23 = fmaxf(d[2], d[3]);
    float m = (lg == 3) ? m01 : fmaxf(m01, m23);   // rows 14,15 excluded (garbage-safe)
    m = fmaxf(m, __shfl_xor(m, 16, 64));
    m = fmaxf(m, __shfl_xor(m, 32, 64));
    return m;
}

// ---------- uniform block: 2-phase conv (2-deep A pipeline) + emb (late-issue) ----------
// r18 champion + T5 setprio around MFMA clusters (zero-register desync lever).
// NO __launch_bounds__ min-waves (r5/r6/r8: force-occupancy => spill/wave cliff).
__global__ void __launch_bounds__(256)
fused_kernel(const int* __restrict__ words, const int* __restrict__ chars,
             const float* __restrict__ W_word, const ushort* __restrict__ ws,
             float* __restrict__ out) {
    __shared__ __align__(16) ushort tile[TILE_TOT];   // ~33 KB -> 4 blocks/CU (LDS-bound)

    const int tid  = threadIdx.x;
    const int lane = tid & 63;
    const int wave = tid >> 6;

    const ushort* __restrict__ charP = ws;
    const ushort* __restrict__ WO    = ws + CHARP_U16;
    const int block0 = blockIdx.x * WPB;
    const int l15 = lane & 15;
    const int lg  = lane >> 4;
    const int srcblk = (lane & 7) ^ ((lane >> 3) & 7);   // pre-swizzled source block

    // ---- ids prefetch for BOTH halves (wave stages words {wave*2, wave*2+1}/half)
    int ids[2][2][2];
    #pragma unroll
    for (int h = 0; h < 2; h++)
        #pragma unroll
        for (int ww = 0; ww < 2; ww++) {
            const int m = block0 + h * 8 + wave * 2 + ww;
            const int* __restrict__ cbase = chars + ((m & 63) * SENT + (m >> 6)) * WLEN;
            #pragma unroll
            for (int s = 0; s < 2; s++)
                ids[h][ww][s] = cbase[s * 8 + (lane >> 3)];
        }

    // ---- B fragments (latency hides under staging); bias inside K
    short8 B[3][6];
    #pragma unroll
    for (int i = 0; i < 3; i++) {
        int col = (wave + 4 * i) * 16 + l15;                  // <= 191
        #pragma unroll
        for (int s = 0; s < 6; s++)
            B[i][s] = *(const short8*)&WO[col * KPAD + s * 32 + lg * 8];
    }

#define STAGE_HALF(h)                                                         \
    {                                                                         \
        _Pragma("unroll")                                                     \
        for (int ww = 0; ww < 2; ww++) {                                      \
            const int wl = (h) * 8 + wave * 2 + ww;                           \
            _Pragma("unroll")                                                 \
            for (int s = 0; s < 2; s++) {                                     \
                const ushort* src_ = charP + ids[h][ww][s] * 64 + (srcblk << 3); \
                GLOAD16(src_, &tile[wl * 1024 + s * 512]);                    \
            }                                                                 \
        }                                                                     \
    }

    // ---- loop-invariant swizzled LDS read offsets; word stride 1024 u16
    int offA[6];
    #pragma unroll
    for (int s = 0; s < 6; s++) {
        int l  = l15 + (s >> 1);
        int bb = (((s & 1) * 4 + lg) ^ (l & 7));
        offA[s] = l * 64 + (bb << 3);
    }

#define LOAD_A(dst, widx)                                                     \
    {                                                                         \
        const int base_ = (widx) << 10;                                       \
        _Pragma("unroll")                                                     \
        for (int s = 0; s < 6; s++)                                           \
            dst[s] = *(const short8*)&tile[base_ + offA[s]];                  \
    }

#define MFMA_RED_STORE(a_, widx)                                              \
    {                                                                         \
        float4v acc_[3];                                                      \
        _Pragma("unroll")                                                     \
        for (int i = 0; i < 3; i++) acc_[i] = (float4v){0, 0, 0, 0};          \
        __builtin_amdgcn_s_setprio(1);                                        \
        _Pragma("unroll")                                                     \
        for (int s = 0; s < 6; s++)                                           \
            _Pragma("unroll")                                                 \
            for (int i = 0; i < 3; i++)                                       \
                acc_[i] = __builtin_amdgcn_mfma_f32_16x16x32_bf16(            \
                    a_[s], B[i][s], acc_[i], 0, 0, 0);                        \
        __builtin_amdgcn_s_setprio(0);                                        \
        float* obase_ = out + (size_t)(block0 + (widx)) * D_OUT + D_WORDE;    \
        _Pragma("unroll")                                                     \
        for (int i = 0; i < 3; i++) {                                         \
            float mx_ = redmax14(acc_[i], lg);                                \
            if (lane < 16) obase_[(wave + 4 * i) * 16 + lane] = mx_;          \
        }                                                                     \
    }

// 2-deep software-pipelined phase over 8 words (aA/aB rotation)
#define PHASE1_HALF_PIPE(h)                                                   \
    {                                                                         \
        short8 aA[6], aB[6];                                                  \
        LOAD_A(aA, (h) * 8)                                                   \
        _Pragma("unroll 1")                                                   \
        for (int r = (h) * 8; r < (h) * 8 + 8; r += 2) {                      \
            LOAD_A(aB, r + 1)                                                 \
            MFMA_RED_STORE(aA, r)                                             \
            if (r + 2 < (h) * 8 + 8) LOAD_A(aA, r + 2)                        \
            MFMA_RED_STORE(aB, r + 1)                                         \
        }                                                                     \
    }

    // ---- 2-phase pipeline: stage0 | bar | stage1-issue, compute0 | bar | compute1
    STAGE_HALF(0)
    __syncthreads();                       // drains stage0 only (emb not yet issued)
    STAGE_HALF(1)                          // flies under compute of half 0
    PHASE1_HALF_PIPE(0)
    __syncthreads();                       // drains stage1

    // ---- T14 issue-early (AFTER last barrier): 4 word-emb rows -> registers.
    // No barrier follows, so the HBM latency hides under phase1(1)+phase2.
    const int me = block0 + wave * 4;
    const bool tail = lane < (75 - 64);
    float4v e0[4], e1[4];
    #pragma unroll
    for (int r = 0; r < 4; r++) {
        const float4v* __restrict__ src =
            (const float4v*)(W_word + (size_t)words[me + r] * D_WORDE);
        e0[r] = src[lane];
        e1[r] = tail ? src[64 + lane] : (float4v){0, 0, 0, 0};
    }

    PHASE1_HALF_PIPE(1)

    // ---- phase 2: tile 12 (channels 192..199); wave does 4 words (both bufs valid)
    {
        short8 B12[6];
        #pragma unroll
        for (int s = 0; s < 6; s++)
            B12[s] = *(const short8*)&WO[(192 + l15) * KPAD + s * 32 + lg * 8];

        #pragma unroll 1
        for (int r2 = 0; r2 < 4; r2++) {
            const int widx = wave * 4 + r2;
            short8 a[6];
            LOAD_A(a, widx)
            float4v acc = {0, 0, 0, 0};
            __builtin_amdgcn_s_setprio(1);
            #pragma unroll
            for (int s = 0; s < 6; s++)
                acc = __builtin_amdgcn_mfma_f32_16x16x32_bf16(a[s], B12[s], acc, 0, 0, 0);
            __builtin_amdgcn_s_setprio(0);
            float mx = redmax14(acc, lg);
            if (lane < 8)
                out[(size_t)(block0 + widx) * D_OUT + D_WORDE + 192 + lane] = mx;
        }
    }

    // ---- T14 write-late: emb rows from registers
    #pragma unroll
    for (int r = 0; r < 4; r++) {
        float4v* __restrict__ dst = (float4v*)(out + (size_t)(me + r) * D_OUT);
        dst[lane] = e0[r];
        if (tail) dst[64 + lane] = e1[r];
    }
#undef STAGE_HALF
#undef LOAD_A
#undef MFMA_RED_STORE
#undef PHASE1_HALF_PIPE
}

// ---------- fallbacks (tiny ws): round-1 proven kernels ----------
__global__ void __launch_bounds__(256)
word_emb_kernel(const int* __restrict__ words, const float* __restrict__ W_word,
                float* __restrict__ out) {
    int wave = threadIdx.x >> 6, lane = threadIdx.x & 63;
    int m = blockIdx.x * 4 + wave;
    int idx = words[m];
    const float* __restrict__ src = W_word + (size_t)idx * D_WORDE;
    float* __restrict__ dst = out + (size_t)m * D_OUT;
    for (int j = lane; j < D_WORDE; j += 64) dst[j] = src[j];
}

__global__ void __launch_bounds__(256)
char_conv_f32_kernel(const int* __restrict__ chars, const float* __restrict__ W_char,
                     const float* __restrict__ conv_w, const float* __restrict__ conv_b,
                     float* __restrict__ out) {
    __shared__ __align__(16) float xs[D_CHARE * WLEN];
    __shared__ int ids[WLEN];
    int m = blockIdx.x, s = m >> 6, b = m & 63, tid = threadIdx.x;
    if (tid < WLEN) ids[tid] = chars[(b * SENT + s) * WLEN + tid];
    __syncthreads();
    for (int e = tid; e < D_CHARE * WLEN; e += 256) {
        int c = e >> 4, l = e & 15;
        xs[e] = W_char[ids[l] * D_CHARE + c];
    }
    __syncthreads();
    if (tid < OUT_CH) {
        float acc[NPOS];
        #pragma unroll
        for (int p = 0; p < NPOS; p++) acc[p] = 0.f;
        const float4* xs4 = (const float4*)xs;
        for (int c = 0; c < D_CHARE; c++) {
            float4 a0 = xs4[c*4+0], a1 = xs4[c*4+1], a2 = xs4[c*4+2], a3 = xs4[c*4+3];
            float xr[WLEN] = {a0.x,a0.y,a0.z,a0.w, a1.x,a1.y,a1.z,a1.w,
                              a2.x,a2.y,a2.z,a2.w, a3.x,a3.y,a3.z,a3.w};
            #pragma unroll
            for (int k = 0; k < KSIZE; k++) {
                float wv = conv_w[tid * (D_CHARE * KSIZE) + c * KSIZE + k];
                #pragma unroll
                for (int p = 0; p < NPOS; p++) acc[p] = fmaf(wv, xr[p + k], acc[p]);
            }
        }
        float mx = acc[0];
        #pragma unroll
        for (int p = 1; p < NPOS; p++) mx = fmaxf(mx, acc[p]);
        out[(size_t)m * D_OUT + D_WORDE + tid] = mx + conv_b[tid];
    }
}

extern "C" void kernel_launch(void* const* d_in, const int* in_sizes, int n_in,
                              void* d_out, int out_size, void* d_ws, size_t ws_size,
                              hipStream_t stream) {
    const int*   words  = (const int*)d_in[0];
    const int*   chars  = (const int*)d_in[1];
    const float* W_word = (const float*)d_in[2];
    const float* W_char = (const float*)d_in[3];
    const float* conv_w = (const float*)d_in[4];
    const float* conv_b = (const float*)d_in[5];
    float* out = (float*)d_out;

    if (ws_size >= WS_NEED) {
        ushort* ws = (ushort*)d_ws;
        hipLaunchKernelGGL(prep_kernel,
                           dim3((CHARP_U16 + WO_U16 + 255) / 256), dim3(256), 0, stream,
                           W_char, conv_w, conv_b, ws);
        hipLaunchKernelGGL(fused_kernel, dim3(CONV_BLOCKS), dim3(256), 0, stream,
                           words, chars, W_word, ws, out);
    } else {
        hipLaunchKernelGGL(word_emb_kernel, dim3(NWORDS / 4), dim3(256), 0, stream,
                           words, W_word, out);
        hipLaunchKernelGGL(char_conv_f32_kernel, dim3(NWORDS), dim3(256), 0, stream,
                           chars, W_char, conv_w, conv_b, out);
    }
}

// Round 22
// 33.202 us; speedup vs baseline: 1.9463x; 1.3792x over previous
//
#include <hip/hip_runtime.h>

#define SENT    256
#define BATCH   64
#define WLEN    16
#define D_WORDE 300
#define D_CHARE 50
#define OUT_CH  200
#define KSIZE   3
#define NPOS    14
#define D_OUT   500
#define NWORDS  (SENT * BATCH)

// GEMM geometry (transposed): per position p, M=16 words, N=13x16=208, K=192.
// A[word][kg=kk*64+c] = emb[word][p+kk][c]; 3-row sliding window over p.
// Bias folded into K: charP col63 = 1.0, WO[o][191] = conv_b[o].
#define KPAD      192
#define MPAD      208
#define CHARP_U16 (129 * 64)
#define WO_U16    (MPAD * KPAD)
#define WS_NEED   ((size_t)(CHARP_U16 + WO_U16) * 2)

#define WPB         16                 // words per block (= M of each p-GEMM)
#define TILE_U16    (WPB * 1024)       // 32 KB; 4 blocks/CU
#define CONV_BLOCKS (NWORDS / WPB)     // 1024 blocks x 512 threads

typedef short  short8  __attribute__((ext_vector_type(8)));
typedef ushort ushort8 __attribute__((ext_vector_type(8)));
typedef float  float4v __attribute__((ext_vector_type(4)));

#define GLOAD16(SRC, DST)                                                     \
    __builtin_amdgcn_global_load_lds(                                         \
        (const __attribute__((address_space(1))) void*)(SRC),                 \
        (__attribute__((address_space(3))) void*)(DST), 16, 0, 0)

__device__ __forceinline__ ushort f2bf(float f) {
    unsigned u = __float_as_uint(f);
    u = (u + 0x7FFFu + ((u >> 16) & 1u)) >> 16;   // RNE
    return (ushort)u;
}

// ---------- prep: bf16 char table (col63=1.0) + K-major weights (kg191=bias) ----------
__global__ void prep_kernel(const float* __restrict__ W_char,
                            const float* __restrict__ conv_w,
                            const float* __restrict__ conv_b,
                            ushort* __restrict__ ws) {
    int j = blockIdx.x * 256 + threadIdx.x;
    if (j < CHARP_U16) {
        int r = j >> 6, c = j & 63;
        ushort v = 0;
        if (r < 128) {
            if (c < D_CHARE)      v = f2bf(W_char[r * D_CHARE + c]);
            else if (c == 63)     v = 0x3F80;        // 1.0 bf16 (bias lane)
        }
        ws[j] = v;
    }
    int j2 = j - CHARP_U16;
    if (j2 >= 0 && j2 < WO_U16) {
        int o = j2 / KPAD, kg = j2 - o * KPAD;
        int kk = kg >> 6, c = kg & 63;
        float v = 0.f;
        if (o < OUT_CH) {
            if (c < D_CHARE)      v = conv_w[o * (D_CHARE * KSIZE) + c * KSIZE + kk];
            else if (kg == 191)   v = conv_b[o];     // bias rides K-slot 191
        }
        ws[CHARP_U16 + j2] = f2bf(v);
    }
}

__device__ __forceinline__ float4v fmax4(float4v a, float4v b) {
    float4v r;
    r[0] = fmaxf(a[0], b[0]); r[1] = fmaxf(a[1], b[1]);
    r[2] = fmaxf(a[2], b[2]); r[3] = fmaxf(a[3], b[3]);
    return r;
}

// A-frag read: word l15, LDS row `row`, true granule g (0..7); swizzle ^(row&7)^(word&7)
__device__ __forceinline__ short8 lda(const ushort* __restrict__ tile,
                                      int l15, int row, int g) {
    int pos = g ^ (row & 7) ^ (l15 & 7);
    return *(const short8*)&tile[l15 * 1024 + row * 64 + (pos << 3)];
}

// NT tiles {tbase..}; 14-position sliding-window GEMM with in-register max.
template <int NT>
__device__ __forceinline__ void conv_ploop(int tbase, int lane, int l15, int lg,
                                           const ushort* __restrict__ tile,
                                           const ushort* __restrict__ WO,
                                           float* __restrict__ out, int block0) {
    short8 B[NT][6];
    #pragma unroll
    for (int i = 0; i < NT; i++) {
        int col = (tbase + i) * 16 + l15;                 // <= 207 < MPAD
        #pragma unroll
        for (int s = 0; s < 6; s++)
            B[i][s] = *(const short8*)&WO[col * KPAD + s * 32 + lg * 8];
    }

    // window rows p, p+1, p+2 (two k-halves each)
    short8 a0 = lda(tile, l15, 0, lg),     a1 = lda(tile, l15, 0, 4 + lg);
    short8 a2 = lda(tile, l15, 1, lg),     a3 = lda(tile, l15, 1, 4 + lg);
    short8 a4 = lda(tile, l15, 2, lg),     a5 = lda(tile, l15, 2, 4 + lg);

    float4v mx[NT];
    #pragma unroll
    for (int p = 0; p < NPOS; p++) {
        float4v acc[NT];
        #pragma unroll
        for (int i = 0; i < NT; i++) acc[i] = (float4v){0, 0, 0, 0};
        #pragma unroll
        for (int i = 0; i < NT; i++) acc[i] = __builtin_amdgcn_mfma_f32_16x16x32_bf16(a0, B[i][0], acc[i], 0, 0, 0);
        #pragma unroll
        for (int i = 0; i < NT; i++) acc[i] = __builtin_amdgcn_mfma_f32_16x16x32_bf16(a1, B[i][1], acc[i], 0, 0, 0);
        #pragma unroll
        for (int i = 0; i < NT; i++) acc[i] = __builtin_amdgcn_mfma_f32_16x16x32_bf16(a2, B[i][2], acc[i], 0, 0, 0);
        #pragma unroll
        for (int i = 0; i < NT; i++) acc[i] = __builtin_amdgcn_mfma_f32_16x16x32_bf16(a3, B[i][3], acc[i], 0, 0, 0);
        #pragma unroll
        for (int i = 0; i < NT; i++) acc[i] = __builtin_amdgcn_mfma_f32_16x16x32_bf16(a4, B[i][4], acc[i], 0, 0, 0);
        #pragma unroll
        for (int i = 0; i < NT; i++) acc[i] = __builtin_amdgcn_mfma_f32_16x16x32_bf16(a5, B[i][5], acc[i], 0, 0, 0);

        #pragma unroll
        for (int i = 0; i < NT; i++) mx[i] = (p == 0) ? acc[i] : fmax4(mx[i], acc[i]);

        if (p < NPOS - 1) {          // slide window to rows p+1..p+3
            a0 = a2; a1 = a3; a2 = a4; a3 = a5;
            a4 = lda(tile, l15, p + 3, lg);
            a5 = lda(tile, l15, p + 3, 4 + lg);
        }
    }

    // store: C row = (lane>>4)*4 + reg  ->  word = lg*4 + j  (verified layout)
    #pragma unroll
    for (int i = 0; i < NT; i++) {
        int col = (tbase + i) * 16 + l15;
        if (col < OUT_CH) {
            #pragma unroll
            for (int j = 0; j < 4; j++)
                out[(size_t)(block0 + lg * 4 + j) * D_OUT + D_WORDE + col] = mx[i][j];
        }
    }
}

// ---------- uniform 512-thread block: stage | bar | {6x tile-pair, 1x tile12, 1x emb}
__global__ void __launch_bounds__(512)
fused_kernel(const int* __restrict__ words, const int* __restrict__ chars,
             const float* __restrict__ W_word, const ushort* __restrict__ ws,
             float* __restrict__ out) {
    __shared__ __align__(16) ushort tile[TILE_U16];   // 32 KB -> 4 blocks/CU

    const int tid  = threadIdx.x;
    const int lane = tid & 63;
    const int wave = tid >> 6;          // 0..7
    const int l15  = lane & 15;
    const int lg   = lane >> 4;

    const ushort* __restrict__ charP = ws;
    const ushort* __restrict__ WO    = ws + CHARP_U16;
    const int block0 = blockIdx.x * WPB;

    // ---- stage: every wave stages words {2w, 2w+1}; linear dest, swizzled source
    #pragma unroll
    for (int ww = 0; ww < 2; ww++) {
        const int wl = wave * 2 + ww;
        const int m  = block0 + wl;
        const int* __restrict__ cbase = chars + ((m & 63) * SENT + (m >> 6)) * WLEN;
        const int srcg = (lane & 7) ^ ((lane >> 3) & 7) ^ (wl & 7);
        #pragma unroll
        for (int s = 0; s < 2; s++) {
            const int idv = cbase[s * 8 + (lane >> 3)];
            GLOAD16(charP + idv * 64 + (srcg << 3), &tile[wl * 1024 + s * 512]);
        }
    }
    __syncthreads();                    // the only barrier; waves independent after

    if (wave < 6) {
        conv_ploop<2>(2 * wave, lane, l15, lg, tile, WO, out, block0);   // tiles 0..11
    } else if (wave == 6) {
        conv_ploop<1>(12, lane, l15, lg, tile, WO, out, block0);         // tile 12
    } else {
        // ---- emb wave: 16 rows, 4 in flight (proven r16/r18 pattern)
        const bool tail = lane < (75 - 64);
        #pragma unroll 1
        for (int r4 = 0; r4 < 4; r4++) {
            const int m0 = block0 + r4 * 4;
            float4v e0[4], e1[4];
            #pragma unroll
            for (int j = 0; j < 4; j++) {
                const float4v* __restrict__ src =
                    (const float4v*)(W_word + (size_t)words[m0 + j] * D_WORDE);
                e0[j] = src[lane];
                e1[j] = tail ? src[64 + lane] : (float4v){0, 0, 0, 0};
            }
            #pragma unroll
            for (int j = 0; j < 4; j++) {
                float4v* __restrict__ dst = (float4v*)(out + (size_t)(m0 + j) * D_OUT);
                dst[lane] = e0[j];
                if (tail) dst[64 + lane] = e1[j];
            }
        }
    }
}

// ---------- fallbacks (tiny ws): round-1 proven kernels ----------
__global__ void __launch_bounds__(256)
word_emb_kernel(const int* __restrict__ words, const float* __restrict__ W_word,
                float* __restrict__ out) {
    int wave = threadIdx.x >> 6, lane = threadIdx.x & 63;
    int m = blockIdx.x * 4 + wave;
    int idx = words[m];
    const float* __restrict__ src = W_word + (size_t)idx * D_WORDE;
    float* __restrict__ dst = out + (size_t)m * D_OUT;
    for (int j = lane; j < D_WORDE; j += 64) dst[j] = src[j];
}

__global__ void __launch_bounds__(256)
char_conv_f32_kernel(const int* __restrict__ chars, const float* __restrict__ W_char,
                     const float* __restrict__ conv_w, const float* __restrict__ conv_b,
                     float* __restrict__ out) {
    __shared__ __align__(16) float xs[D_CHARE * WLEN];
    __shared__ int ids[WLEN];
    int m = blockIdx.x, s = m >> 6, b = m & 63, tid = threadIdx.x;
    if (tid < WLEN) ids[tid] = chars[(b * SENT + s) * WLEN + tid];
    __syncthreads();
    for (int e = tid; e < D_CHARE * WLEN; e += 256) {
        int c = e >> 4, l = e & 15;
        xs[e] = W_char[ids[l] * D_CHARE + c];
    }
    __syncthreads();
    if (tid < OUT_CH) {
        float acc[NPOS];
        #pragma unroll
        for (int p = 0; p < NPOS; p++) acc[p] = 0.f;
        const float4* xs4 = (const float4*)xs;
        for (int c = 0; c < D_CHARE; c++) {
            float4 a0 = xs4[c*4+0], a1 = xs4[c*4+1], a2 = xs4[c*4+2], a3 = xs4[c*4+3];
            float xr[WLEN] = {a0.x,a0.y,a0.z,a0.w, a1.x,a1.y,a1.z,a1.w,
                              a2.x,a2.y,a2.z,a2.w, a3.x,a3.y,a3.z,a3.w};
            #pragma unroll
            for (int k = 0; k < KSIZE; k++) {
                float wv = conv_w[tid * (D_CHARE * KSIZE) + c * KSIZE + k];
                #pragma unroll
                for (int p = 0; p < NPOS; p++) acc[p] = fmaf(wv, xr[p + k], acc[p]);
            }
        }
        float mx = acc[0];
        #pragma unroll
        for (int p = 1; p < NPOS; p++) mx = fmaxf(mx, acc[p]);
        out[(size_t)m * D_OUT + D_WORDE + tid] = mx + conv_b[tid];
    }
}

extern "C" void kernel_launch(void* const* d_in, const int* in_sizes, int n_in,
                              void* d_out, int out_size, void* d_ws, size_t ws_size,
                              hipStream_t stream) {
    const int*   words  = (const int*)d_in[0];
    const int*   chars  = (const int*)d_in[1];
    const float* W_word = (const float*)d_in[2];
    const float* W_char = (const float*)d_in[3];
    const float* conv_w = (const float*)d_in[4];
    const float* conv_b = (const float*)d_in[5];
    float* out = (float*)d_out;

    if (ws_size >= WS_NEED) {
        ushort* ws = (ushort*)d_ws;
        hipLaunchKernelGGL(prep_kernel,
                           dim3((CHARP_U16 + WO_U16 + 255) / 256), dim3(256), 0, stream,
                           W_char, conv_w, conv_b, ws);
        hipLaunchKernelGGL(fused_kernel, dim3(CONV_BLOCKS), dim3(512), 0, stream,
                           words, chars, W_word, ws, out);
    } else {
        hipLaunchKernelGGL(word_emb_kernel, dim3(NWORDS / 4), dim3(256), 0, stream,
                           words, W_word, out);
        hipLaunchKernelGGL(char_conv_f32_kernel, dim3(NWORDS), dim3(256), 0, stream,
                           chars, W_char, conv_w, conv_b, out);
    }
}